// Round 2
// baseline (126.158 us; speedup 1.0000x reference)
//
#include <hip/hip_runtime.h>

// CrossNet: xi = x0; for l in 0..2: s = dot(xi, W[l]); xi = x0*s + B[l] + xi
// BATCH=16384, DIM=1024, ORDER=3, fp32.
// One 64-lane wave per row; 16 floats/lane of x0/xi in registers.
// Memory-bound: 64 MiB read (x0) + 64 MiB write (out), zero reuse ->
// nontemporal load/store to cut L2 retention/write-allocate pressure.
// W/B (12 KiB each) stay cached: reused by all 16384 waves.

#define CN_BATCH 16384
#define CN_DIM   1024
#define CN_ORDER 3

typedef float v4f __attribute__((ext_vector_type(4)));

__global__ __launch_bounds__(256) void
crossnet_kernel(const float* __restrict__ x0,
                const float* __restrict__ W,
                const float* __restrict__ B,
                float* __restrict__ out)
{
    const int tid  = threadIdx.x;
    const int wave = tid >> 6;          // 0..3 waves per block
    const int lane = tid & 63;
    const int row  = blockIdx.x * 4 + wave;

    const v4f* __restrict__ xr =
        reinterpret_cast<const v4f*>(x0 + (size_t)row * CN_DIM) + lane;

    // lane handles elements chunk*256 + lane*4 .. +3 (16 B/lane, coalesced)
    v4f x[4], xi[4];
#pragma unroll
    for (int c = 0; c < 4; ++c) {
        x[c]  = __builtin_nontemporal_load(xr + c * 64);
        xi[c] = x[c];
    }

#pragma unroll
    for (int l = 0; l < CN_ORDER; ++l) {
        const v4f* __restrict__ wl =
            reinterpret_cast<const v4f*>(W + l * CN_DIM) + lane;
        const v4f* __restrict__ bl =
            reinterpret_cast<const v4f*>(B + l * CN_DIM) + lane;

        // per-lane partial dot product (16 elements)
        float s = 0.f;
#pragma unroll
        for (int c = 0; c < 4; ++c) {
            const v4f w = wl[c * 64];
            s = fmaf(xi[c].x, w.x, s);
            s = fmaf(xi[c].y, w.y, s);
            s = fmaf(xi[c].z, w.z, s);
            s = fmaf(xi[c].w, w.w, s);
        }

        // 64-lane butterfly reduction — every lane ends with the full sum
#pragma unroll
        for (int off = 1; off < 64; off <<= 1)
            s += __shfl_xor(s, off, 64);

        // xi += x0 * s + B[l]
#pragma unroll
        for (int c = 0; c < 4; ++c) {
            const v4f b = bl[c * 64];
            xi[c].x = fmaf(x[c].x, s, xi[c].x + b.x);
            xi[c].y = fmaf(x[c].y, s, xi[c].y + b.y);
            xi[c].z = fmaf(x[c].z, s, xi[c].z + b.z);
            xi[c].w = fmaf(x[c].w, s, xi[c].w + b.w);
        }
    }

    v4f* __restrict__ orow =
        reinterpret_cast<v4f*>(out + (size_t)row * CN_DIM) + lane;
#pragma unroll
    for (int c = 0; c < 4; ++c)
        __builtin_nontemporal_store(xi[c], orow + c * 64);
}

extern "C" void kernel_launch(void* const* d_in, const int* in_sizes, int n_in,
                              void* d_out, int out_size, void* d_ws, size_t ws_size,
                              hipStream_t stream)
{
    const float* x0 = (const float*)d_in[0];   // [16384, 1024]
    const float* W  = (const float*)d_in[1];   // [3, 1024]
    const float* B  = (const float*)d_in[2];   // [3, 1024]
    float* out      = (float*)d_out;           // [16384, 1024]

    const int rows_per_block = 4;              // 4 waves of 64 lanes
    dim3 grid(CN_BATCH / rows_per_block);
    dim3 block(256);
    crossnet_kernel<<<grid, block, 0, stream>>>(x0, W, B, out);
}